// Round 2
// baseline (614.752 us; speedup 1.0000x reference)
//
#include <hip/hip_runtime.h>

typedef _Float16 f16;
typedef __attribute__((ext_vector_type(2))) _Float16 f16x2;
typedef __attribute__((ext_vector_type(4))) _Float16 f16x4;
typedef __attribute__((ext_vector_type(8))) _Float16 f16x8;
typedef __attribute__((ext_vector_type(4))) float f32x4;

#define BM 128
#define BN 128
#define BK 32

__device__ __forceinline__ void gl_lds16(const void* g, void* l) {
    __builtin_amdgcn_global_load_lds(
        (const __attribute__((address_space(1))) void*)g,
        (__attribute__((address_space(3))) void*)l, 16, 0, 0);
}

__device__ __forceinline__ float dot2f(f16x2 a, f16x2 b, float c) {
#if __has_builtin(__builtin_amdgcn_fdot2)
    return __builtin_amdgcn_fdot2(a, b, c, false);
#else
    return c + (float)a[0]*(float)b[0] + (float)a[1]*(float)b[1];
#endif
}

// ---------------------------------------------------------------------------
// Transpose + f32->f16 convert: src (K,N) f32 row-major -> dst (N,Kpad) f16
// rows k >= K are zero-padded. Grid: (Kpad/64, N/64), 256 threads.
// ---------------------------------------------------------------------------
__global__ void convt_kernel(const float* __restrict__ src, f16* __restrict__ dst,
                             int K, int N, int Kpad)
{
    __shared__ float tile[64][65];
    int k0 = blockIdx.x * 64;
    int n0 = blockIdx.y * 64;
    int tid = threadIdx.x;
    #pragma unroll
    for (int it = 0; it < 16; ++it) {
        int idx = it * 256 + tid;
        int kr = idx >> 6, nc = idx & 63;
        float v = 0.f;
        if (k0 + kr < K) v = src[(size_t)(k0 + kr) * N + n0 + nc];
        tile[kr][nc] = v;
    }
    __syncthreads();
    #pragma unroll
    for (int it = 0; it < 16; ++it) {
        int idx = it * 256 + tid;
        int nr = idx >> 6, kc = idx & 63;
        dst[(size_t)(n0 + nr) * Kpad + k0 + kc] = (f16)tile[kc][nr];
    }
}

// ---------------------------------------------------------------------------
// Bottom layer 0: (B,13) @ (13,512) + b, relu, f16 out. One thread per output.
// ---------------------------------------------------------------------------
__global__ void bot0_kernel(const float* __restrict__ xin, const float* __restrict__ w,
                            const float* __restrict__ bias, f16* __restrict__ out)
{
    int t = blockIdx.x * 256 + threadIdx.x;
    int b = t >> 9, n = t & 511;
    float acc = bias[n];
    #pragma unroll
    for (int k = 0; k < 13; ++k) acc += xin[b * 13 + k] * w[k * 512 + n];
    out[(size_t)b * 512 + n] = (f16)fmaxf(acc, 0.f);
}

// ---------------------------------------------------------------------------
// MFMA f16 GEMM: C(M,N) = relu(A(M,K) @ W(K,N) + bias), W given transposed
// as WT(N,K). A,WT,C f16; bias f32; f32 accumulate.
// 128x128 tile, BK=32, 4 waves (2x2), 4x4 16x16x32 fragments per wave.
// global_load_lds(16B) staging, XOR k-slot swizzle (both-sides) for LDS reads.
// Grid: (N/128, M/128), 256 threads. Requires M%128==0, N%128==0, K%32==0.
// ---------------------------------------------------------------------------
__global__ void gemm_f16(const f16* __restrict__ A, const f16* __restrict__ WT,
                         const float* __restrict__ bias, f16* __restrict__ C,
                         int N, int K)
{
    __shared__ __align__(16) f16 lsA[BM * BK];
    __shared__ __align__(16) f16 lsB[BN * BK];
    int tid  = threadIdx.x;
    int lane = tid & 63;
    int wave = tid >> 6;
    int brow = blockIdx.y * BM;
    int bcol = blockIdx.x * BN;
    int wr = wave >> 1, wc = wave & 1;

    f32x4 acc[4][4] = {};

    int rsel = lane & 15;
    int k8   = lane >> 4;

    int nK = K / BK;
    for (int kt = 0; kt < nK; ++kt) {
        int k0 = kt * BK;
        #pragma unroll
        for (int i = 0; i < 2; ++i) {
            int flat = i * 256 + tid;
            int row  = flat >> 2;          // 0..127
            int slot = flat & 3;           // 16B slot within 64B row
            int sg   = slot ^ ((row >> 1) & 3);   // pre-swizzled global source
            gl_lds16(A  + (size_t)(brow + row) * K + k0 + sg * 8, lsA + flat * 8);
            gl_lds16(WT + (size_t)(bcol + row) * K + k0 + sg * 8, lsB + flat * 8);
        }
        __syncthreads();

        f16x8 aF[4], bF[4];
        #pragma unroll
        for (int m = 0; m < 4; ++m) {
            int ra = wr * 64 + m * 16 + rsel;
            int sa = k8 ^ ((ra >> 1) & 3);
            aF[m] = *(const f16x8*)(lsA + ra * 32 + sa * 8);
        }
        #pragma unroll
        for (int n = 0; n < 4; ++n) {
            int rb = wc * 64 + n * 16 + rsel;
            int sb = k8 ^ ((rb >> 1) & 3);
            bF[n] = *(const f16x8*)(lsB + rb * 32 + sb * 8);
        }
        #pragma unroll
        for (int m = 0; m < 4; ++m)
            #pragma unroll
            for (int n = 0; n < 4; ++n)
                acc[m][n] = __builtin_amdgcn_mfma_f32_16x16x32_f16(aF[m], bF[n], acc[m][n], 0, 0, 0);
        __syncthreads();
    }

    // epilogue: C/D layout col = lane&15, row = (lane>>4)*4 + reg
    #pragma unroll
    for (int n = 0; n < 4; ++n) {
        int col = bcol + wc * 64 + n * 16 + (lane & 15);
        float bv = bias[col];
        #pragma unroll
        for (int m = 0; m < 4; ++m) {
            int rowb = brow + wr * 64 + m * 16 + (lane >> 4) * 4;
            #pragma unroll
            for (int r = 0; r < 4; ++r) {
                float v = acc[m][n][r] + bv;
                C[(size_t)(rowb + r) * N + col] = (f16)fmaxf(v, 0.f);
            }
        }
    }
}

// ---------------------------------------------------------------------------
// Interaction: per sample, gather bot_out + 26 embedding rows, compute the
// 351 strict-lower-triangle Gram dots (K=128), write x = [bot_out | interact |
// zero pad to 512] as f16. One block (256 thr) per sample.
// ---------------------------------------------------------------------------
__global__ void interact_kernel(const f16* __restrict__ botout,
                                const float* __restrict__ emb,
                                const int* __restrict__ sparse,
                                f16* __restrict__ x, int V)
{
    __shared__ f16 fe[27][132];   // +4 f16 pad: stride 264B breaks bank aliasing
    int b   = blockIdx.x;
    int tid = threadIdx.x;
    for (int t = tid; t < 27 * 128; t += 256) {
        int r = t >> 7, d = t & 127;
        f16 v;
        if (r == 0) {
            v = botout[(size_t)b * 128 + d];
            x[(size_t)b * 512 + d] = v;
        } else {
            int e = r - 1;
            int idx = sparse[b * 26 + e];
            v = (f16)emb[((size_t)e * V + idx) * 128 + d];
        }
        fe[r][d] = v;
    }
    if (tid < 33) x[(size_t)b * 512 + 479 + tid] = (f16)0.f;
    __syncthreads();
    for (int p = tid; p < 351; p += 256) {
        int i = (int)((1.0f + sqrtf(1.0f + 8.0f * (float)p)) * 0.5f);
        while ((i * (i - 1)) / 2 > p) --i;
        while (((i + 1) * i) / 2 <= p) ++i;
        int j = p - (i * (i - 1)) / 2;
        float acc = 0.f;
        #pragma unroll
        for (int d = 0; d < 64; ++d) {
            f16x2 u = *(const f16x2*)&fe[i][2 * d];
            f16x2 w = *(const f16x2*)&fe[j][2 * d];
            acc = dot2f(u, w, acc);
        }
        x[(size_t)b * 512 + 128 + p] = (f16)acc;
    }
}

// ---------------------------------------------------------------------------
// Final layer: (B,256) @ (256,1) + b, relu, f32 out. One wave per row.
// ---------------------------------------------------------------------------
__global__ void top4_kernel(const f16* __restrict__ a, const float* __restrict__ w,
                            const float* __restrict__ bias, float* __restrict__ out)
{
    int wave = threadIdx.x >> 6, lane = threadIdx.x & 63;
    int b = blockIdx.x * 4 + wave;
    f16x4 av = *(const f16x4*)(a + (size_t)b * 256 + lane * 4);
    float acc = 0.f;
    #pragma unroll
    for (int k = 0; k < 4; ++k) acc += (float)av[k] * w[lane * 4 + k];
    #pragma unroll
    for (int off = 32; off; off >>= 1) acc += __shfl_xor(acc, off, 64);
    if (lane == 0) out[b] = fmaxf(acc + bias[0], 0.f);
}

// ---------------------------------------------------------------------------
extern "C" void kernel_launch(void* const* d_in, const int* in_sizes, int n_in,
                              void* d_out, int out_size, void* d_ws, size_t ws_size,
                              hipStream_t stream)
{
    (void)n_in; (void)out_size; (void)ws_size;
    const float* dense  = (const float*)d_in[0];
    const int*   sparse = (const int*)  d_in[1];
    const float* emb    = (const float*)d_in[2];
    const float* bw0 = (const float*)d_in[3];
    const float* bb0 = (const float*)d_in[4];
    const float* bw1 = (const float*)d_in[5];
    const float* bb1 = (const float*)d_in[6];
    const float* bw2 = (const float*)d_in[7];
    const float* bb2 = (const float*)d_in[8];
    const float* tw0 = (const float*)d_in[9];
    const float* tb0 = (const float*)d_in[10];
    const float* tw1 = (const float*)d_in[11];
    const float* tb1 = (const float*)d_in[12];
    const float* tw2 = (const float*)d_in[13];
    const float* tb2 = (const float*)d_in[14];
    const float* tw3 = (const float*)d_in[15];
    const float* tb3 = (const float*)d_in[16];
    const float* tw4 = (const float*)d_in[17];
    const float* tb4 = (const float*)d_in[18];
    float* out = (float*)d_out;

    const int B = in_sizes[0] / 13;
    const int V = in_sizes[2] / (26 * 128);

    char* ws = (char*)d_ws;
    size_t off = 0;
    auto alloc = [&](size_t bytes) {
        char* p = ws + off;
        off += (bytes + 255) & ~(size_t)255;
        return p;
    };
    // lifetime-aliased slots
    f16* S1   = (f16*)alloc((size_t)B * 1024 * 2); // act0 (B,512) then t2 (B,1024)
    f16* t1   = (f16*)alloc((size_t)B * 1024 * 2); // (B,1024)
    f16* S3   = (f16*)alloc((size_t)B * 512 * 2);  // x (B,512) then t3 (B,512)
    f16* S4   = (f16*)alloc((size_t)B * 256 * 2);  // act1 (B,256) then t4 (B,256)
    f16* act2 = (f16*)alloc((size_t)B * 128 * 2);  // bot_out (B,128)
    f16* bw1T = (f16*)alloc((size_t)256 * 512 * 2);
    f16* bw2T = (f16*)alloc((size_t)128 * 256 * 2);
    f16* tw0T = (f16*)alloc((size_t)1024 * 512 * 2);
    f16* tw1T = (f16*)alloc((size_t)1024 * 1024 * 2);
    f16* tw2T = (f16*)alloc((size_t)512 * 1024 * 2);
    f16* tw3T = (f16*)alloc((size_t)256 * 512 * 2);
    f16* act0 = S1; f16* t2 = S1;
    f16* x    = S3; f16* t3 = S3;
    f16* act1 = S4; f16* t4 = S4;

    // weight conversion (transposed f16, K zero-padded where needed)
    convt_kernel<<<dim3( 512/64,  256/64), 256, 0, stream>>>(bw1, bw1T,  512,  256,  512);
    convt_kernel<<<dim3( 256/64,  128/64), 256, 0, stream>>>(bw2, bw2T,  256,  128,  256);
    convt_kernel<<<dim3( 512/64, 1024/64), 256, 0, stream>>>(tw0, tw0T,  479, 1024,  512);
    convt_kernel<<<dim3(1024/64, 1024/64), 256, 0, stream>>>(tw1, tw1T, 1024, 1024, 1024);
    convt_kernel<<<dim3(1024/64,  512/64), 256, 0, stream>>>(tw2, tw2T, 1024,  512, 1024);
    convt_kernel<<<dim3( 512/64,  256/64), 256, 0, stream>>>(tw3, tw3T,  512,  256,  512);

    bot0_kernel<<<(B * 512) / 256, 256, 0, stream>>>(dense, bw0, bb0, act0);
    gemm_f16<<<dim3( 256/128, B/128), 256, 0, stream>>>(act0, bw1T, bb1, act1,  256,  512);
    gemm_f16<<<dim3( 128/128, B/128), 256, 0, stream>>>(act1, bw2T, bb2, act2,  128,  256);
    interact_kernel<<<B, 256, 0, stream>>>(act2, emb, sparse, x, V);
    gemm_f16<<<dim3(1024/128, B/128), 256, 0, stream>>>(x,  tw0T, tb0, t1, 1024,  512);
    gemm_f16<<<dim3(1024/128, B/128), 256, 0, stream>>>(t1, tw1T, tb1, t2, 1024, 1024);
    gemm_f16<<<dim3( 512/128, B/128), 256, 0, stream>>>(t2, tw2T, tb2, t3,  512, 1024);
    gemm_f16<<<dim3( 256/128, B/128), 256, 0, stream>>>(t3, tw3T, tb3, t4,  256,  512);
    top4_kernel<<<B / 4, 256, 0, stream>>>(t4, tw4, tb4, out);
}

// Round 3
// 581.348 us; speedup vs baseline: 1.0575x; 1.0575x over previous
//
#include <hip/hip_runtime.h>

typedef _Float16 f16;
typedef __attribute__((ext_vector_type(2))) _Float16 f16x2;
typedef __attribute__((ext_vector_type(4))) _Float16 f16x4;
typedef __attribute__((ext_vector_type(8))) _Float16 f16x8;
typedef __attribute__((ext_vector_type(4))) float f32x4;

#define BM 128
#define BN 128
#define BK 32

#define TBM 256
#define TBN 256
#define TBK 64

__device__ __forceinline__ void gl_lds16(const void* g, void* l) {
    __builtin_amdgcn_global_load_lds(
        (const __attribute__((address_space(1))) void*)g,
        (__attribute__((address_space(3))) void*)l, 16, 0, 0);
}

__device__ __forceinline__ float dot2f(f16x2 a, f16x2 b, float c) {
#if __has_builtin(__builtin_amdgcn_fdot2)
    return __builtin_amdgcn_fdot2(a, b, c, false);
#else
    return c + (float)a[0]*(float)b[0] + (float)a[1]*(float)b[1];
#endif
}

// ---------------------------------------------------------------------------
// Transpose + f32->f16 convert: src (K,N) f32 row-major -> dst (N,Kpad) f16
// ---------------------------------------------------------------------------
__global__ void convt_kernel(const float* __restrict__ src, f16* __restrict__ dst,
                             int K, int N, int Kpad)
{
    __shared__ float tile[64][65];
    int k0 = blockIdx.x * 64;
    int n0 = blockIdx.y * 64;
    int tid = threadIdx.x;
    #pragma unroll
    for (int it = 0; it < 16; ++it) {
        int idx = it * 256 + tid;
        int kr = idx >> 6, nc = idx & 63;
        float v = 0.f;
        if (k0 + kr < K) v = src[(size_t)(k0 + kr) * N + n0 + nc];
        tile[kr][nc] = v;
    }
    __syncthreads();
    #pragma unroll
    for (int it = 0; it < 16; ++it) {
        int idx = it * 256 + tid;
        int nr = idx >> 6, kc = idx & 63;
        dst[(size_t)(n0 + nr) * Kpad + k0 + kc] = (f16)tile[kc][nr];
    }
}

// ---------------------------------------------------------------------------
// Bottom layer 0: (B,13) @ (13,512) + b, relu, f16 out.
// ---------------------------------------------------------------------------
__global__ void bot0_kernel(const float* __restrict__ xin, const float* __restrict__ w,
                            const float* __restrict__ bias, f16* __restrict__ out)
{
    int t = blockIdx.x * 256 + threadIdx.x;
    int b = t >> 9, n = t & 511;
    float acc = bias[n];
    #pragma unroll
    for (int k = 0; k < 13; ++k) acc += xin[b * 13 + k] * w[k * 512 + n];
    out[(size_t)b * 512 + n] = (f16)fmaxf(acc, 0.f);
}

// ---------------------------------------------------------------------------
// 128x128 MFMA f16 GEMM (m97-style). Used for small-N layers.
// ---------------------------------------------------------------------------
__global__ void gemm_f16(const f16* __restrict__ A, const f16* __restrict__ WT,
                         const float* __restrict__ bias, f16* __restrict__ C,
                         int N, int K)
{
    __shared__ __align__(16) f16 lsA[BM * BK];
    __shared__ __align__(16) f16 lsB[BN * BK];
    int tid  = threadIdx.x;
    int lane = tid & 63;
    int wave = tid >> 6;
    int brow = blockIdx.y * BM;
    int bcol = blockIdx.x * BN;
    int wr = wave >> 1, wc = wave & 1;

    f32x4 acc[4][4] = {};
    int rsel = lane & 15;
    int k8   = lane >> 4;

    int nK = K / BK;
    for (int kt = 0; kt < nK; ++kt) {
        int k0 = kt * BK;
        #pragma unroll
        for (int i = 0; i < 2; ++i) {
            int flat = i * 256 + tid;
            int row  = flat >> 2;
            int slot = flat & 3;
            int sg   = slot ^ ((row >> 1) & 3);
            gl_lds16(A  + (size_t)(brow + row) * K + k0 + sg * 8, lsA + flat * 8);
            gl_lds16(WT + (size_t)(bcol + row) * K + k0 + sg * 8, lsB + flat * 8);
        }
        __syncthreads();

        f16x8 aF[4], bF[4];
        #pragma unroll
        for (int m = 0; m < 4; ++m) {
            int ra = wr * 64 + m * 16 + rsel;
            int sa = k8 ^ ((ra >> 1) & 3);
            aF[m] = *(const f16x8*)(lsA + ra * 32 + sa * 8);
        }
        #pragma unroll
        for (int n = 0; n < 4; ++n) {
            int rb = wc * 64 + n * 16 + rsel;
            int sb = k8 ^ ((rb >> 1) & 3);
            bF[n] = *(const f16x8*)(lsB + rb * 32 + sb * 8);
        }
        #pragma unroll
        for (int m = 0; m < 4; ++m)
            #pragma unroll
            for (int n = 0; n < 4; ++n)
                acc[m][n] = __builtin_amdgcn_mfma_f32_16x16x32_f16(aF[m], bF[n], acc[m][n], 0, 0, 0);
        __syncthreads();
    }

    #pragma unroll
    for (int n = 0; n < 4; ++n) {
        int col = bcol + wc * 64 + n * 16 + (lane & 15);
        float bv = bias[col];
        #pragma unroll
        for (int m = 0; m < 4; ++m) {
            int rowb = brow + wr * 64 + m * 16 + (lane >> 4) * 4;
            #pragma unroll
            for (int r = 0; r < 4; ++r) {
                float v = acc[m][n][r] + bv;
                C[(size_t)(rowb + r) * N + col] = (f16)fmaxf(v, 0.f);
            }
        }
    }
}

// ---------------------------------------------------------------------------
// 256x256 MFMA f16 GEMM, BK=64, 8 waves (2Mx4N), double-buffered LDS (128 KiB),
// one barrier per K-step (T3-minimum 2-phase), 8-slot XOR swizzle both-sides,
// XCD-chunked block swizzle. Per-wave output 128x64 (8x4 16x16 frags).
// Requires M%256==0, N%256==0, K%64==0, grid total %8==0.
// ---------------------------------------------------------------------------
__global__ __launch_bounds__(512, 2) void gemm256_f16(
    const f16* __restrict__ A, const f16* __restrict__ WT,
    const float* __restrict__ bias, f16* __restrict__ C, int N, int K)
{
    __shared__ __align__(16) f16 ls[2][2 * TBM * TBK];   // 128 KiB
    int tid  = threadIdx.x;
    int lane = tid & 63;
    int wid  = tid >> 6;
    int wm = wid >> 2, wn = wid & 3;

    // XCD-chunked bijective block swizzle (total % 8 == 0 guaranteed by caller)
    int nbx = gridDim.x;
    int flat = blockIdx.y * nbx + blockIdx.x;
    int nchunk = (nbx * gridDim.y) >> 3;
    int nf = (flat & 7) * nchunk + (flat >> 3);
    int bx = nf % nbx, by = nf / nbx;
    int brow = by * TBM, bcol = bx * TBN;

    f32x4 acc[8][4] = {};
    int rsel = lane & 15;
    int k8   = lane >> 4;

    const size_t szK = (size_t)K;
    auto stage = [&](int buf, int kt) {
        const f16* gA = A  + (size_t)brow * szK + kt * TBK;
        const f16* gB = WT + (size_t)bcol * szK + kt * TBK;
        f16* dA = &ls[buf][0];
        f16* dB = &ls[buf][TBM * TBK];
        #pragma unroll
        for (int i = 0; i < 4; ++i) {
            int fl  = i * 512 + tid;
            int row = fl >> 3;            // 0..255
            int sl  = fl & 7;             // 16B slot in 128B row
            int sg  = sl ^ (row & 7);     // inverse-swizzled global source
            gl_lds16(gA + (size_t)row * szK + sg * 8, dA + fl * 8);
            gl_lds16(gB + (size_t)row * szK + sg * 8, dB + fl * 8);
        }
    };

    int nK = K / TBK;
    stage(0, 0);
    __syncthreads();                       // drains vmcnt(0)

    for (int kt = 0; kt < nK; ++kt) {
        int cur = kt & 1;
        if (kt + 1 < nK) stage(cur ^ 1, kt + 1);   // loads stay in flight over MFMA
        const f16* pA = &ls[cur][0];
        const f16* pB = &ls[cur][TBM * TBK];
        #pragma unroll
        for (int ks = 0; ks < 2; ++ks) {
            f16x8 aF[8], bF[4];
            #pragma unroll
            for (int m = 0; m < 8; ++m) {
                int ra = wm * 128 + m * 16 + rsel;
                int s  = (ks * 4 + k8) ^ (ra & 7);
                aF[m] = *(const f16x8*)(pA + ra * 64 + s * 8);
            }
            #pragma unroll
            for (int n = 0; n < 4; ++n) {
                int rb = wn * 64 + n * 16 + rsel;
                int s  = (ks * 4 + k8) ^ (rb & 7);
                bF[n] = *(const f16x8*)(pB + rb * 64 + s * 8);
            }
            #pragma unroll
            for (int m = 0; m < 8; ++m)
                #pragma unroll
                for (int n = 0; n < 4; ++n)
                    acc[m][n] = __builtin_amdgcn_mfma_f32_16x16x32_f16(aF[m], bF[n], acc[m][n], 0, 0, 0);
        }
        __syncthreads();                   // single barrier per K-step
    }

    #pragma unroll
    for (int n = 0; n < 4; ++n) {
        int col = bcol + wn * 64 + n * 16 + (lane & 15);
        float bv = bias[col];
        #pragma unroll
        for (int m = 0; m < 8; ++m) {
            int rowb = brow + wm * 128 + m * 16 + (lane >> 4) * 4;
            #pragma unroll
            for (int r = 0; r < 4; ++r)
                C[(size_t)(rowb + r) * N + col] = (f16)fmaxf(acc[m][n][r] + bv, 0.f);
        }
    }
}

// ---------------------------------------------------------------------------
// Interaction: gather bot_out + 26 embedding rows, 351 Gram dots, concat.
// ---------------------------------------------------------------------------
__global__ void interact_kernel(const f16* __restrict__ botout,
                                const float* __restrict__ emb,
                                const int* __restrict__ sparse,
                                f16* __restrict__ x, int V)
{
    __shared__ f16 fe[27][132];
    int b   = blockIdx.x;
    int tid = threadIdx.x;
    for (int t = tid; t < 27 * 128; t += 256) {
        int r = t >> 7, d = t & 127;
        f16 v;
        if (r == 0) {
            v = botout[(size_t)b * 128 + d];
            x[(size_t)b * 512 + d] = v;
        } else {
            int e = r - 1;
            int idx = sparse[b * 26 + e];
            v = (f16)emb[((size_t)e * V + idx) * 128 + d];
        }
        fe[r][d] = v;
    }
    if (tid < 33) x[(size_t)b * 512 + 479 + tid] = (f16)0.f;
    __syncthreads();
    for (int p = tid; p < 351; p += 256) {
        int i = (int)((1.0f + sqrtf(1.0f + 8.0f * (float)p)) * 0.5f);
        while ((i * (i - 1)) / 2 > p) --i;
        while (((i + 1) * i) / 2 <= p) ++i;
        int j = p - (i * (i - 1)) / 2;
        float acc = 0.f;
        #pragma unroll
        for (int d = 0; d < 64; ++d) {
            f16x2 u = *(const f16x2*)&fe[i][2 * d];
            f16x2 w = *(const f16x2*)&fe[j][2 * d];
            acc = dot2f(u, w, acc);
        }
        x[(size_t)b * 512 + 128 + p] = (f16)acc;
    }
}

// ---------------------------------------------------------------------------
// Final layer: (B,256) @ (256,1) + b, relu, f32 out.
// ---------------------------------------------------------------------------
__global__ void top4_kernel(const f16* __restrict__ a, const float* __restrict__ w,
                            const float* __restrict__ bias, float* __restrict__ out)
{
    int wave = threadIdx.x >> 6, lane = threadIdx.x & 63;
    int b = blockIdx.x * 4 + wave;
    f16x4 av = *(const f16x4*)(a + (size_t)b * 256 + lane * 4);
    float acc = 0.f;
    #pragma unroll
    for (int k = 0; k < 4; ++k) acc += (float)av[k] * w[lane * 4 + k];
    #pragma unroll
    for (int off = 32; off; off >>= 1) acc += __shfl_xor(acc, off, 64);
    if (lane == 0) out[b] = fmaxf(acc + bias[0], 0.f);
}

// ---------------------------------------------------------------------------
extern "C" void kernel_launch(void* const* d_in, const int* in_sizes, int n_in,
                              void* d_out, int out_size, void* d_ws, size_t ws_size,
                              hipStream_t stream)
{
    (void)n_in; (void)out_size; (void)ws_size;
    const float* dense  = (const float*)d_in[0];
    const int*   sparse = (const int*)  d_in[1];
    const float* emb    = (const float*)d_in[2];
    const float* bw0 = (const float*)d_in[3];
    const float* bb0 = (const float*)d_in[4];
    const float* bw1 = (const float*)d_in[5];
    const float* bb1 = (const float*)d_in[6];
    const float* bw2 = (const float*)d_in[7];
    const float* bb2 = (const float*)d_in[8];
    const float* tw0 = (const float*)d_in[9];
    const float* tb0 = (const float*)d_in[10];
    const float* tw1 = (const float*)d_in[11];
    const float* tb1 = (const float*)d_in[12];
    const float* tw2 = (const float*)d_in[13];
    const float* tb2 = (const float*)d_in[14];
    const float* tw3 = (const float*)d_in[15];
    const float* tb3 = (const float*)d_in[16];
    const float* tw4 = (const float*)d_in[17];
    const float* tb4 = (const float*)d_in[18];
    float* out = (float*)d_out;

    const int B = in_sizes[0] / 13;
    const int V = in_sizes[2] / (26 * 128);

    char* ws = (char*)d_ws;
    size_t off = 0;
    auto alloc = [&](size_t bytes) {
        char* p = ws + off;
        off += (bytes + 255) & ~(size_t)255;
        return p;
    };
    f16* S1   = (f16*)alloc((size_t)B * 1024 * 2); // act0 (B,512) then t2 (B,1024)
    f16* t1   = (f16*)alloc((size_t)B * 1024 * 2); // (B,1024)
    f16* S3   = (f16*)alloc((size_t)B * 512 * 2);  // x (B,512) then t3 (B,512)
    f16* S4   = (f16*)alloc((size_t)B * 256 * 2);  // act1 (B,256) then t4 (B,256)
    f16* act2 = (f16*)alloc((size_t)B * 128 * 2);  // bot_out (B,128)
    f16* bw1T = (f16*)alloc((size_t)256 * 512 * 2);
    f16* bw2T = (f16*)alloc((size_t)128 * 256 * 2);
    f16* tw0T = (f16*)alloc((size_t)1024 * 512 * 2);
    f16* tw1T = (f16*)alloc((size_t)1024 * 1024 * 2);
    f16* tw2T = (f16*)alloc((size_t)512 * 1024 * 2);
    f16* tw3T = (f16*)alloc((size_t)256 * 512 * 2);
    f16* act0 = S1; f16* t2 = S1;
    f16* x    = S3; f16* t3 = S3;
    f16* act1 = S4; f16* t4 = S4;

    convt_kernel<<<dim3( 512/64,  256/64), 256, 0, stream>>>(bw1, bw1T,  512,  256,  512);
    convt_kernel<<<dim3( 256/64,  128/64), 256, 0, stream>>>(bw2, bw2T,  256,  128,  256);
    convt_kernel<<<dim3( 512/64, 1024/64), 256, 0, stream>>>(tw0, tw0T,  479, 1024,  512);
    convt_kernel<<<dim3(1024/64, 1024/64), 256, 0, stream>>>(tw1, tw1T, 1024, 1024, 1024);
    convt_kernel<<<dim3(1024/64,  512/64), 256, 0, stream>>>(tw2, tw2T, 1024,  512, 1024);
    convt_kernel<<<dim3( 512/64,  256/64), 256, 0, stream>>>(tw3, tw3T,  512,  256,  512);

    bot0_kernel<<<(B * 512) / 256, 256, 0, stream>>>(dense, bw0, bb0, act0);
    gemm_f16<<<dim3( 256/128, B/128), 256, 0, stream>>>(act0, bw1T, bb1, act1,  256,  512);
    gemm_f16<<<dim3( 128/128, B/128), 256, 0, stream>>>(act1, bw2T, bb2, act2,  128,  256);
    interact_kernel<<<B, 256, 0, stream>>>(act2, emb, sparse, x, V);
    gemm256_f16<<<dim3(1024/256, B/256), 512, 0, stream>>>(x,  tw0T, tb0, t1, 1024,  512);
    gemm256_f16<<<dim3(1024/256, B/256), 512, 0, stream>>>(t1, tw1T, tb1, t2, 1024, 1024);
    gemm256_f16<<<dim3( 512/256, B/256), 512, 0, stream>>>(t2, tw2T, tb2, t3,  512, 1024);
    gemm_f16<<<dim3( 256/128, B/128), 256, 0, stream>>>(t3, tw3T, tb3, t4,  256,  512);
    top4_kernel<<<B / 4, 256, 0, stream>>>(t4, tw4, tb4, out);
}

// Round 4
// 397.882 us; speedup vs baseline: 1.5451x; 1.4611x over previous
//
#include <hip/hip_runtime.h>

typedef _Float16 f16;
typedef __attribute__((ext_vector_type(2))) _Float16 f16x2;
typedef __attribute__((ext_vector_type(4))) _Float16 f16x4;
typedef __attribute__((ext_vector_type(8))) _Float16 f16x8;
typedef __attribute__((ext_vector_type(4))) float f32x4;

#define BM 128
#define BN 128
#define BK 32

#define TBM 256
#define TBN 256
#define TBK 64

__device__ __forceinline__ void gl_lds16(const void* g, void* l) {
    __builtin_amdgcn_global_load_lds(
        (const __attribute__((address_space(1))) void*)g,
        (__attribute__((address_space(3))) void*)l, 16, 0, 0);
}

// ---------------------------------------------------------------------------
// Fused transpose+convert for all 6 weights: src (K,N) f32 -> dst (N,Kpad) f16
// ---------------------------------------------------------------------------
struct ConvtDesc { const float* src; f16* dst; int K, N, Kpad, tileOff; };
struct ConvtArgs { ConvtDesc d[6]; };

__global__ void convt6_kernel(ConvtArgs args)
{
    __shared__ float tile[64][65];
    int bid = blockIdx.x;
    int w = 0;
    #pragma unroll
    for (int i = 1; i < 6; ++i) if (bid >= args.d[i].tileOff) w = i;
    const float* __restrict__ src = args.d[w].src;
    f16* __restrict__ dst = args.d[w].dst;
    int K = args.d[w].K, N = args.d[w].N, Kpad = args.d[w].Kpad;
    int local = bid - args.d[w].tileOff;
    int tk = Kpad >> 6;
    int k0 = (local % tk) * 64;
    int n0 = (local / tk) * 64;
    int tid = threadIdx.x;
    #pragma unroll
    for (int it = 0; it < 16; ++it) {
        int idx = it * 256 + tid;
        int kr = idx >> 6, nc = idx & 63;
        float v = 0.f;
        if (k0 + kr < K) v = src[(size_t)(k0 + kr) * N + n0 + nc];
        tile[kr][nc] = v;
    }
    __syncthreads();
    #pragma unroll
    for (int it = 0; it < 16; ++it) {
        int idx = it * 256 + tid;
        int nr = idx >> 6, kc = idx & 63;
        dst[(size_t)(n0 + nr) * Kpad + k0 + kc] = (f16)tile[kc][nr];
    }
}

// ---------------------------------------------------------------------------
// Bottom layer 0: (B,13) @ (13,512) + b, relu, f16 out.
// ---------------------------------------------------------------------------
__global__ void bot0_kernel(const float* __restrict__ xin, const float* __restrict__ w,
                            const float* __restrict__ bias, f16* __restrict__ out)
{
    int t = blockIdx.x * 256 + threadIdx.x;
    int b = t >> 9, n = t & 511;
    float acc = bias[n];
    #pragma unroll
    for (int k = 0; k < 13; ++k) acc += xin[b * 13 + k] * w[k * 512 + n];
    out[(size_t)b * 512 + n] = (f16)fmaxf(acc, 0.f);
}

// ---------------------------------------------------------------------------
// 128x128 MFMA f16 GEMM (m97-style). Small-N layers.
// ---------------------------------------------------------------------------
__global__ void gemm_f16(const f16* __restrict__ A, const f16* __restrict__ WT,
                         const float* __restrict__ bias, f16* __restrict__ C,
                         int N, int K)
{
    __shared__ __align__(16) f16 lsA[BM * BK];
    __shared__ __align__(16) f16 lsB[BN * BK];
    int tid  = threadIdx.x;
    int lane = tid & 63;
    int wave = tid >> 6;
    int brow = blockIdx.y * BM;
    int bcol = blockIdx.x * BN;
    int wr = wave >> 1, wc = wave & 1;

    f32x4 acc[4][4] = {};
    int rsel = lane & 15;
    int k8   = lane >> 4;

    int nK = K / BK;
    for (int kt = 0; kt < nK; ++kt) {
        int k0 = kt * BK;
        #pragma unroll
        for (int i = 0; i < 2; ++i) {
            int flat = i * 256 + tid;
            int row  = flat >> 2;
            int slot = flat & 3;
            int sg   = slot ^ ((row >> 1) & 3);
            gl_lds16(A  + (size_t)(brow + row) * K + k0 + sg * 8, lsA + flat * 8);
            gl_lds16(WT + (size_t)(bcol + row) * K + k0 + sg * 8, lsB + flat * 8);
        }
        __syncthreads();

        f16x8 aF[4], bF[4];
        #pragma unroll
        for (int m = 0; m < 4; ++m) {
            int ra = wr * 64 + m * 16 + rsel;
            int sa = k8 ^ ((ra >> 1) & 3);
            aF[m] = *(const f16x8*)(lsA + ra * 32 + sa * 8);
        }
        #pragma unroll
        for (int n = 0; n < 4; ++n) {
            int rb = wc * 64 + n * 16 + rsel;
            int sb = k8 ^ ((rb >> 1) & 3);
            bF[n] = *(const f16x8*)(lsB + rb * 32 + sb * 8);
        }
        #pragma unroll
        for (int m = 0; m < 4; ++m)
            #pragma unroll
            for (int n = 0; n < 4; ++n)
                acc[m][n] = __builtin_amdgcn_mfma_f32_16x16x32_f16(aF[m], bF[n], acc[m][n], 0, 0, 0);
        __syncthreads();
    }

    #pragma unroll
    for (int n = 0; n < 4; ++n) {
        int col = bcol + wc * 64 + n * 16 + (lane & 15);
        float bv = bias[col];
        #pragma unroll
        for (int m = 0; m < 4; ++m) {
            int rowb = brow + wr * 64 + m * 16 + (lane >> 4) * 4;
            #pragma unroll
            for (int r = 0; r < 4; ++r) {
                float v = acc[m][n][r] + bv;
                C[(size_t)(rowb + r) * N + col] = (f16)fmaxf(v, 0.f);
            }
        }
    }
}

// ---------------------------------------------------------------------------
// 256x256 MFMA f16 GEMM, BK=64, 8 waves, double-buffered LDS, 2-phase.
// ---------------------------------------------------------------------------
__global__ __launch_bounds__(512, 2) void gemm256_f16(
    const f16* __restrict__ A, const f16* __restrict__ WT,
    const float* __restrict__ bias, f16* __restrict__ C, int N, int K)
{
    __shared__ __align__(16) f16 ls[2][2 * TBM * TBK];   // 128 KiB
    int tid  = threadIdx.x;
    int lane = tid & 63;
    int wid  = tid >> 6;
    int wm = wid >> 2, wn = wid & 3;

    int nbx = gridDim.x;
    int flat = blockIdx.y * nbx + blockIdx.x;
    int nchunk = (nbx * gridDim.y) >> 3;
    int nf = (flat & 7) * nchunk + (flat >> 3);
    int bx = nf % nbx, by = nf / nbx;
    int brow = by * TBM, bcol = bx * TBN;

    f32x4 acc[8][4] = {};
    int rsel = lane & 15;
    int k8   = lane >> 4;

    const size_t szK = (size_t)K;
    auto stage = [&](int buf, int kt) {
        const f16* gA = A  + (size_t)brow * szK + kt * TBK;
        const f16* gB = WT + (size_t)bcol * szK + kt * TBK;
        f16* dA = &ls[buf][0];
        f16* dB = &ls[buf][TBM * TBK];
        #pragma unroll
        for (int i = 0; i < 4; ++i) {
            int fl  = i * 512 + tid;
            int row = fl >> 3;
            int sl  = fl & 7;
            int sg  = sl ^ (row & 7);
            gl_lds16(gA + (size_t)row * szK + sg * 8, dA + fl * 8);
            gl_lds16(gB + (size_t)row * szK + sg * 8, dB + fl * 8);
        }
    };

    int nK = K / TBK;
    stage(0, 0);
    __syncthreads();

    for (int kt = 0; kt < nK; ++kt) {
        int cur = kt & 1;
        if (kt + 1 < nK) stage(cur ^ 1, kt + 1);
        const f16* pA = &ls[cur][0];
        const f16* pB = &ls[cur][TBM * TBK];
        #pragma unroll
        for (int ks = 0; ks < 2; ++ks) {
            f16x8 aF[8], bF[4];
            #pragma unroll
            for (int m = 0; m < 8; ++m) {
                int ra = wm * 128 + m * 16 + rsel;
                int s  = (ks * 4 + k8) ^ (ra & 7);
                aF[m] = *(const f16x8*)(pA + ra * 64 + s * 8);
            }
            #pragma unroll
            for (int n = 0; n < 4; ++n) {
                int rb = wn * 64 + n * 16 + rsel;
                int s  = (ks * 4 + k8) ^ (rb & 7);
                bF[n] = *(const f16x8*)(pB + rb * 64 + s * 8);
            }
            #pragma unroll
            for (int m = 0; m < 8; ++m)
                #pragma unroll
                for (int n = 0; n < 4; ++n)
                    acc[m][n] = __builtin_amdgcn_mfma_f32_16x16x32_f16(aF[m], bF[n], acc[m][n], 0, 0, 0);
        }
        __syncthreads();
    }

    #pragma unroll
    for (int n = 0; n < 4; ++n) {
        int col = bcol + wn * 64 + n * 16 + (lane & 15);
        float bv = bias[col];
        #pragma unroll
        for (int m = 0; m < 8; ++m) {
            int rowb = brow + wm * 128 + m * 16 + (lane >> 4) * 4;
            #pragma unroll
            for (int r = 0; r < 4; ++r)
                C[(size_t)(rowb + r) * N + col] = (f16)fmaxf(acc[m][n][r] + bv, 0.f);
        }
    }
}

// ---------------------------------------------------------------------------
// MFMA interaction: 4 samples/block (256 thr), one wave per sample.
// Gram Z = F F^T via 16x16x32 f16 MFMA; A-frag == B-frag registers.
// F rows stored with 16-slot XOR swizzle (slot ^= row&15) for conflict-free
// fragment reads. Output row [bot_out | 351 tril | 0-pad] packed in LDS then
// stored coalesced.
// ---------------------------------------------------------------------------
__global__ void interact_mfma(const f16* __restrict__ botout,
                              const float* __restrict__ emb,
                              const int* __restrict__ sparse,
                              f16* __restrict__ x, int V)
{
    __shared__ __align__(16) f16 F[4][32][128];   // 32 KiB (rows 27-31 garbage ok)
    __shared__ __align__(16) f16 xs[4][512];      // 4 KiB
    int tid  = threadIdx.x;
    int lane = tid & 63, wave = tid >> 6;
    int b0 = blockIdx.x * 4;

    // phase 1: stage 4 samples x 27 rows x 16 slots (16B each), swizzled
    for (int t = tid; t < 4 * 27 * 16; t += 256) {
        int s   = t / (27 * 16);
        int rem = t - s * (27 * 16);
        int r   = rem >> 4;
        int c   = rem & 15;
        int b   = b0 + s;
        f16x8 v;
        if (r == 0) {
            v = *(const f16x8*)(botout + (size_t)b * 128 + c * 8);
        } else {
            const float* src = emb + ((size_t)(r - 1) * V + sparse[b * 26 + (r - 1)]) * 128 + c * 8;
            #pragma unroll
            for (int e = 0; e < 8; ++e) v[e] = (f16)src[e];
        }
        *(f16x8*)(&F[s][r][(c ^ (r & 15)) * 8]) = v;
    }
    __syncthreads();

    // phase 2: Gram via MFMA (quadrants (0,0),(1,0),(1,1); (0,1) is upper-tri)
    f32x4 a00 = {}, a10 = {}, a11 = {};
    int rl = lane & 15, ch = lane >> 4;
    #pragma unroll
    for (int ks = 0; ks < 4; ++ks) {
        int c = ks * 4 + ch;
        f16x8 f0 = *(const f16x8*)(&F[wave][rl]     [(c ^ rl) * 8]);
        f16x8 f1 = *(const f16x8*)(&F[wave][16 + rl][(c ^ rl) * 8]);
        a00 = __builtin_amdgcn_mfma_f32_16x16x32_f16(f0, f0, a00, 0, 0, 0);
        a10 = __builtin_amdgcn_mfma_f32_16x16x32_f16(f1, f0, a10, 0, 0, 0);
        a11 = __builtin_amdgcn_mfma_f32_16x16x32_f16(f1, f1, a11, 0, 0, 0);
    }

    // phase 3: scatter C -> packed x row. C/D: col=lane&15, row=(lane>>4)*4+r
    #pragma unroll
    for (int r = 0; r < 4; ++r) {
        int i = ch * 4 + r, j = rl;
        if (i > j) xs[wave][128 + (i * (i - 1)) / 2 + j] = (f16)a00[r];
    }
    #pragma unroll
    for (int r = 0; r < 4; ++r) {
        int i = 16 + ch * 4 + r, j = rl;
        if (i < 27) xs[wave][128 + (i * (i - 1)) / 2 + j] = (f16)a10[r];
    }
    #pragma unroll
    for (int r = 0; r < 4; ++r) {
        int i = 16 + ch * 4 + r, j = 16 + rl;
        if (i < 27 && j < i) xs[wave][128 + (i * (i - 1)) / 2 + j] = (f16)a11[r];
    }
    // bot_out copy (row 0 is swizzle-identity) + zero pad
    #pragma unroll
    for (int d = lane; d < 128; d += 64) xs[wave][d] = F[wave][0][d];
    if (lane < 33) xs[wave][479 + lane] = (f16)0;
    __syncthreads();

    // phase 4: coalesced store (16B/lane)
    {
        int b = b0 + wave;
        f16x8 v = *(const f16x8*)(&xs[wave][lane * 8]);
        *(f16x8*)(x + (size_t)b * 512 + lane * 8) = v;
    }
}

// ---------------------------------------------------------------------------
// Final layer: (B,256) @ (256,1) + b, relu, f32 out.
// ---------------------------------------------------------------------------
__global__ void top4_kernel(const f16* __restrict__ a, const float* __restrict__ w,
                            const float* __restrict__ bias, float* __restrict__ out)
{
    int wave = threadIdx.x >> 6, lane = threadIdx.x & 63;
    int b = blockIdx.x * 4 + wave;
    f16x4 av = *(const f16x4*)(a + (size_t)b * 256 + lane * 4);
    float acc = 0.f;
    #pragma unroll
    for (int k = 0; k < 4; ++k) acc += (float)av[k] * w[lane * 4 + k];
    #pragma unroll
    for (int off = 32; off; off >>= 1) acc += __shfl_xor(acc, off, 64);
    if (lane == 0) out[b] = fmaxf(acc + bias[0], 0.f);
}

// ---------------------------------------------------------------------------
extern "C" void kernel_launch(void* const* d_in, const int* in_sizes, int n_in,
                              void* d_out, int out_size, void* d_ws, size_t ws_size,
                              hipStream_t stream)
{
    (void)n_in; (void)out_size; (void)ws_size;
    const float* dense  = (const float*)d_in[0];
    const int*   sparse = (const int*)  d_in[1];
    const float* emb    = (const float*)d_in[2];
    const float* bw0 = (const float*)d_in[3];
    const float* bb0 = (const float*)d_in[4];
    const float* bw1 = (const float*)d_in[5];
    const float* bb1 = (const float*)d_in[6];
    const float* bw2 = (const float*)d_in[7];
    const float* bb2 = (const float*)d_in[8];
    const float* tw0 = (const float*)d_in[9];
    const float* tb0 = (const float*)d_in[10];
    const float* tw1 = (const float*)d_in[11];
    const float* tb1 = (const float*)d_in[12];
    const float* tw2 = (const float*)d_in[13];
    const float* tb2 = (const float*)d_in[14];
    const float* tw3 = (const float*)d_in[15];
    const float* tb3 = (const float*)d_in[16];
    const float* tw4 = (const float*)d_in[17];
    const float* tb4 = (const float*)d_in[18];
    float* out = (float*)d_out;

    const int B = in_sizes[0] / 13;
    const int V = in_sizes[2] / (26 * 128);

    char* ws = (char*)d_ws;
    size_t off = 0;
    auto alloc = [&](size_t bytes) {
        char* p = ws + off;
        off += (bytes + 255) & ~(size_t)255;
        return p;
    };
    f16* S1   = (f16*)alloc((size_t)B * 1024 * 2); // act0 (B,512) then t2 (B,1024)
    f16* t1   = (f16*)alloc((size_t)B * 1024 * 2); // (B,1024)
    f16* S3   = (f16*)alloc((size_t)B * 512 * 2);  // x (B,512) then t3 (B,512)
    f16* S4   = (f16*)alloc((size_t)B * 256 * 2);  // act1 (B,256) then t4 (B,256)
    f16* act2 = (f16*)alloc((size_t)B * 128 * 2);  // bot_out (B,128)
    f16* bw1T = (f16*)alloc((size_t)256 * 512 * 2);
    f16* bw2T = (f16*)alloc((size_t)128 * 256 * 2);
    f16* tw0T = (f16*)alloc((size_t)1024 * 512 * 2);
    f16* tw1T = (f16*)alloc((size_t)1024 * 1024 * 2);
    f16* tw2T = (f16*)alloc((size_t)512 * 1024 * 2);
    f16* tw3T = (f16*)alloc((size_t)256 * 512 * 2);
    f16* act0 = S1; f16* t2 = S1;
    f16* x    = S3; f16* t3 = S3;
    f16* act1 = S4; f16* t4 = S4;

    // fused weight conversion: tile counts 32,8,128,256,128,32 (prefix offsets)
    ConvtArgs ca;
    ca.d[0] = { bw1, bw1T,  512,  256,  512,   0 };
    ca.d[1] = { bw2, bw2T,  256,  128,  256,  32 };
    ca.d[2] = { tw0, tw0T,  479, 1024,  512,  40 };
    ca.d[3] = { tw1, tw1T, 1024, 1024, 1024, 168 };
    ca.d[4] = { tw2, tw2T, 1024,  512, 1024, 424 };
    ca.d[5] = { tw3, tw3T,  512,  256,  512, 552 };
    convt6_kernel<<<584, 256, 0, stream>>>(ca);

    bot0_kernel<<<(B * 512) / 256, 256, 0, stream>>>(dense, bw0, bb0, act0);
    gemm_f16<<<dim3( 256/128, B/128), 256, 0, stream>>>(act0, bw1T, bb1, act1,  256,  512);
    gemm_f16<<<dim3( 128/128, B/128), 256, 0, stream>>>(act1, bw2T, bb2, act2,  128,  256);
    interact_mfma<<<B / 4, 256, 0, stream>>>(act2, emb, sparse, x, V);
    gemm256_f16<<<dim3(1024/256, B/256), 512, 0, stream>>>(x,  tw0T, tb0, t1, 1024,  512);
    gemm256_f16<<<dim3(1024/256, B/256), 512, 0, stream>>>(t1, tw1T, tb1, t2, 1024, 1024);
    gemm256_f16<<<dim3( 512/256, B/256), 512, 0, stream>>>(t2, tw2T, tb2, t3,  512, 1024);
    gemm_f16<<<dim3( 256/128, B/128), 256, 0, stream>>>(t3, tw3T, tb3, t4,  256,  512);
    top4_kernel<<<B / 4, 256, 0, stream>>>(t4, tw4, tb4, out);
}